// Round 1
// baseline (650.164 us; speedup 1.0000x reference)
//
#include <hip/hip_runtime.h>
#include <stdint.h>

#define DIM 2048
#define SEQ 2048
#define NHEADS 16
#define HDIM 128
#define BSZ 2
#define ROWS (BSZ*SEQ)   // 4096

typedef uint16_t u16;
typedef __attribute__((ext_vector_type(8))) short bf16x8;   // 8 bf16 in 4 VGPRs (guide §3)
typedef __attribute__((ext_vector_type(4))) float fx4;
typedef __attribute__((ext_vector_type(4))) uint16_t u16x4;

__device__ inline u16 f2bf(float f) {
  union { float f; uint32_t u; } v; v.f = f;
  uint32_t u = v.u;
  u += 0x7FFFu + ((u >> 16) & 1u);   // RNE (inputs are finite; NaN path not needed)
  return (u16)(u >> 16);
}
__device__ inline float bf2f(u16 h) {
  union { uint32_t u; float f; } v; v.u = ((uint32_t)h) << 16;
  return v.f;
}

// ---------------------------------------------------------------- convert
__global__ __launch_bounds__(256) void cvt_kernel(const float* __restrict__ src,
                                                  u16* __restrict__ dst, int n4) {
  int i = blockIdx.x * 256 + threadIdx.x;
  if (i >= n4) return;
  fx4 f = *(const fx4*)(src + (size_t)i * 4);
  u16x4 o;
  o[0] = f2bf(f[0]); o[1] = f2bf(f[1]); o[2] = f2bf(f[2]); o[3] = f2bf(f[3]);
  *(u16x4*)(dst + (size_t)i * 4) = o;
}

// ---------------------------------------------------------------- GEMM: C[M,N] = A[M,K] * B[N,K]^T
// 128x128 tile, BK=32, 4 waves in 2x2, each wave 4x4 grid of 16x16x32 MFMAs.
// LDS padded to 40 (80B rows) -> 2-way banks on b128 frag reads (free).
__device__ inline void gemm128_core(const u16* __restrict__ A, const u16* __restrict__ B,
                                    u16 (&As)[128][40], u16 (&Bs)[128][40],
                                    fx4 (&acc)[4][4], int M0, int N0) {
  const int tid  = threadIdx.x;
  const int lane = tid & 63;
  const int wave = tid >> 6;
  const int wm = (wave >> 1) * 64;
  const int wn = (wave & 1) * 64;
  const int l16 = lane & 15;
  const int q8  = (lane >> 4) * 8;
#pragma unroll
  for (int tm = 0; tm < 4; ++tm)
#pragma unroll
    for (int tn = 0; tn < 4; ++tn) acc[tm][tn] = fx4{0.f, 0.f, 0.f, 0.f};

  for (int k0 = 0; k0 < DIM; k0 += 32) {
    __syncthreads();
#pragma unroll
    for (int i = 0; i < 2; ++i) {
      int c = i * 256 + tid;          // 0..511 chunks of 8 elems
      int r = c >> 2;                 // 0..127
      int col = (c & 3) * 8;          // 0,8,16,24
      *(bf16x8*)&As[r][col] = *(const bf16x8*)(A + (size_t)(M0 + r) * DIM + k0 + col);
      *(bf16x8*)&Bs[r][col] = *(const bf16x8*)(B + (size_t)(N0 + r) * DIM + k0 + col);
    }
    __syncthreads();
    bf16x8 af[4], bfr[4];
#pragma unroll
    for (int t = 0; t < 4; ++t) {
      af[t]  = *(const bf16x8*)&As[wm + t * 16 + l16][q8];
      bfr[t] = *(const bf16x8*)&Bs[wn + t * 16 + l16][q8];
    }
#pragma unroll
    for (int tm = 0; tm < 4; ++tm)
#pragma unroll
      for (int tn = 0; tn < 4; ++tn)
        acc[tm][tn] = __builtin_amdgcn_mfma_f32_16x16x32_bf16(af[tm], bfr[tn], acc[tm][tn], 0, 0, 0);
  }
}

__global__ __launch_bounds__(256) void gemm_qkv(const u16* __restrict__ A,
    const u16* __restrict__ B0, const u16* __restrict__ B1, const u16* __restrict__ B2,
    u16* __restrict__ C0, u16* __restrict__ C1, u16* __restrict__ C2) {
  __shared__ __align__(16) u16 As[128][40];
  __shared__ __align__(16) u16 Bs[128][40];
  const u16* B = (blockIdx.z == 0) ? B0 : (blockIdx.z == 1) ? B1 : B2;
  u16* C       = (blockIdx.z == 0) ? C0 : (blockIdx.z == 1) ? C1 : C2;
  const int M0 = blockIdx.y * 128, N0 = blockIdx.x * 128;
  fx4 acc[4][4];
  gemm128_core(A, B, As, Bs, acc, M0, N0);
  const int lane = threadIdx.x & 63, wave = threadIdx.x >> 6;
  const int wm = (wave >> 1) * 64, wn = (wave & 1) * 64;
  const int l16 = lane & 15, quad = lane >> 4;
#pragma unroll
  for (int tm = 0; tm < 4; ++tm)
#pragma unroll
    for (int tn = 0; tn < 4; ++tn)
#pragma unroll
      for (int r = 0; r < 4; ++r) {
        size_t row = (size_t)(M0 + wm + tm * 16 + quad * 4 + r);
        size_t col = (size_t)(N0 + wn + tn * 16 + l16);
        C[row * DIM + col] = f2bf(acc[tm][tn][r]);
      }
}

__global__ __launch_bounds__(256) void gemm_out(const u16* __restrict__ A,
                                                const u16* __restrict__ B,
                                                float* __restrict__ C) {
  __shared__ __align__(16) u16 As[128][40];
  __shared__ __align__(16) u16 Bs[128][40];
  const int M0 = blockIdx.y * 128, N0 = blockIdx.x * 128;
  fx4 acc[4][4];
  gemm128_core(A, B, As, Bs, acc, M0, N0);
  const int lane = threadIdx.x & 63, wave = threadIdx.x >> 6;
  const int wm = (wave >> 1) * 64, wn = (wave & 1) * 64;
  const int l16 = lane & 15, quad = lane >> 4;
#pragma unroll
  for (int tm = 0; tm < 4; ++tm)
#pragma unroll
    for (int tn = 0; tn < 4; ++tn)
#pragma unroll
      for (int r = 0; r < 4; ++r) {
        size_t row = (size_t)(M0 + wm + tm * 16 + quad * 4 + r);
        size_t col = (size_t)(N0 + wn + tn * 16 + l16);
        C[row * DIM + col] = acc[tm][tn][r];
      }
}

// ---------------------------------------------------------------- RoPE (in-place on bf16 Q,K)
__global__ __launch_bounds__(256) void rope_kernel(u16* __restrict__ q, u16* __restrict__ k,
                                                   const float* __restrict__ fcos,
                                                   const float* __restrict__ fsin) {
  int idx = blockIdx.x * 256 + threadIdx.x;      // 0 .. 2*ROWS*1024-1
  int t = idx >> 22;                             // ROWS*1024 = 2^22
  int p_all = idx & ((1 << 22) - 1);
  u16* ptr = t ? k : q;
  int row = p_all >> 10;       // 0..4095
  int r   = p_all & 1023;
  int h   = r >> 6;
  int p   = r & 63;
  int s   = row & (SEQ - 1);
  size_t base = (size_t)row * DIM + h * HDIM + 2 * p;
  float a = bf2f(ptr[base]), b = bf2f(ptr[base + 1]);
  float c = fcos[s * 64 + p], sn = fsin[s * 64 + p];
  ptr[base]     = f2bf(a * c - b * sn);
  ptr[base + 1] = f2bf(a * sn + b * c);
}

// ---------------------------------------------------------------- flash attention (bf16 MFMA)
// Block: 4 waves, 64 q-rows (16/wave). KV tiles of 64. Causal: only kt <= qt.
// Ks[kv][d] row-major (B-operand of QK^T reads kv-row, d-contiguous).
// Vt[d][kv] transposed (B-operand of PV reads d-row, kv-contiguous).
// Ps per-wave: C-layout -> LDS -> A-layout round trip (m120 recipe).
__global__ __launch_bounds__(256) void attn_kernel(const u16* __restrict__ qm,
                                                   const u16* __restrict__ km,
                                                   const u16* __restrict__ vm,
                                                   u16* __restrict__ ao) {
  __shared__ __align__(16) u16 Ks[64][136];   // pad 136: 272B rows, 2-way banks
  __shared__ __align__(16) u16 Vt[128][72];   // pad 72: 144B rows
  __shared__ __align__(16) u16 Ps[4][16][72];
  const int tid = threadIdx.x;
  const int lane = tid & 63, wave = tid >> 6;
  const int l16 = lane & 15, quad = lane >> 4;
  const int qt = blockIdx.x;
  const int bh = blockIdx.y;
  const int b = bh >> 4, h = bh & 15;
  const int q0 = qt * 64;
  const size_t brow = (size_t)b * SEQ;
  const int hc = h * HDIM;

  bf16x8 aq[4];
  {
    size_t qbase = (brow + q0 + wave * 16 + l16) * DIM + hc;
#pragma unroll
    for (int dc = 0; dc < 4; ++dc)
      aq[dc] = *(const bf16x8*)(qm + qbase + dc * 32 + quad * 8);
  }
  fx4 o[8];
#pragma unroll
  for (int i = 0; i < 8; ++i) o[i] = fx4{0.f, 0.f, 0.f, 0.f};
  float mr[4], lr[4];
#pragma unroll
  for (int r = 0; r < 4; ++r) { mr[r] = -3e38f; lr[r] = 0.f; }

  for (int kt = 0; kt <= qt; ++kt) {
    const int kv0 = kt * 64;
    __syncthreads();   // prior iteration's LDS reads done
    // K tile: coalesced row copy
#pragma unroll
    for (int i = 0; i < 4; ++i) {
      int c = i * 256 + tid;
      int r = c >> 4;              // 0..63
      int d0 = (c & 15) * 8;       // 0..120
      *(bf16x8*)&Ks[r][d0] = *(const bf16x8*)(km + (brow + kv0 + r) * DIM + hc + d0);
    }
    // V tile transposed: lanes vary kv-row so LDS scatter is 2-way (free)
#pragma unroll
    for (int i = 0; i < 4; ++i) {
      int c = i * 256 + tid;
      int d0 = (c >> 6) * 8;       // 0..120
      int r = c & 63;              // 0..63
      bf16x8 v8 = *(const bf16x8*)(vm + (brow + kv0 + r) * DIM + hc + d0);
#pragma unroll
      for (int j = 0; j < 8; ++j) Vt[d0 + j][r] = (u16)v8[j];
    }
    __syncthreads();
    // S = Q K^T (scaled)
    fx4 s[4];
#pragma unroll
    for (int tn = 0; tn < 4; ++tn) {
      fx4 acc = fx4{0.f, 0.f, 0.f, 0.f};
#pragma unroll
      for (int dc = 0; dc < 4; ++dc) {
        bf16x8 bk = *(const bf16x8*)&Ks[tn * 16 + l16][dc * 32 + quad * 8];
        acc = __builtin_amdgcn_mfma_f32_16x16x32_bf16(aq[dc], bk, acc, 0, 0, 0);
      }
      s[tn] = acc * 0.08838834764831845f;   // 1/sqrt(128)
    }
    // causal mask
#pragma unroll
    for (int tn = 0; tn < 4; ++tn) {
      int kvpos = kv0 + tn * 16 + l16;
#pragma unroll
      for (int r = 0; r < 4; ++r) {
        int qpos = q0 + wave * 16 + quad * 4 + r;
        if (kvpos > qpos) s[tn][r] = -1e30f;
      }
    }
    // online softmax (rows live in 16-lane groups at reg r)
    float alpha[4];
#pragma unroll
    for (int r = 0; r < 4; ++r) {
      float t = fmaxf(fmaxf(s[0][r], s[1][r]), fmaxf(s[2][r], s[3][r]));
      t = fmaxf(t, __shfl_xor(t, 1));
      t = fmaxf(t, __shfl_xor(t, 2));
      t = fmaxf(t, __shfl_xor(t, 4));
      t = fmaxf(t, __shfl_xor(t, 8));
      float mnew = fmaxf(mr[r], t);
      alpha[r] = __expf(mr[r] - mnew);
      float sm = 0.f;
#pragma unroll
      for (int tn = 0; tn < 4; ++tn) {
        float p = __expf(s[tn][r] - mnew);
        s[tn][r] = p;
        sm += p;
      }
      sm += __shfl_xor(sm, 1);
      sm += __shfl_xor(sm, 2);
      sm += __shfl_xor(sm, 4);
      sm += __shfl_xor(sm, 8);
      lr[r] = lr[r] * alpha[r] + sm;
      mr[r] = mnew;
    }
    // P: C-layout -> LDS (per-wave buffer)
#pragma unroll
    for (int tn = 0; tn < 4; ++tn)
#pragma unroll
      for (int r = 0; r < 4; ++r)
        Ps[wave][quad * 4 + r][tn * 16 + l16] = f2bf(s[tn][r]);
    // rescale O
#pragma unroll
    for (int nt = 0; nt < 8; ++nt) {
      fx4 t = o[nt];
      t[0] *= alpha[0]; t[1] *= alpha[1]; t[2] *= alpha[2]; t[3] *= alpha[3];
      o[nt] = t;
    }
    __syncthreads();   // Ps visible (also orders Vt for safety)
    // O += P V
#pragma unroll
    for (int t2 = 0; t2 < 2; ++t2) {
      bf16x8 ap = *(const bf16x8*)&Ps[wave][l16][t2 * 32 + quad * 8];
#pragma unroll
      for (int nt = 0; nt < 8; ++nt) {
        bf16x8 bv = *(const bf16x8*)&Vt[nt * 16 + l16][t2 * 32 + quad * 8];
        o[nt] = __builtin_amdgcn_mfma_f32_16x16x32_bf16(ap, bv, o[nt], 0, 0, 0);
      }
    }
  }
  // epilogue: O / l -> bf16
#pragma unroll
  for (int nt = 0; nt < 8; ++nt)
#pragma unroll
    for (int r = 0; r < 4; ++r) {
      float val = o[nt][r] / lr[r];
      size_t row = brow + q0 + wave * 16 + quad * 4 + r;
      ao[row * DIM + hc + nt * 16 + l16] = f2bf(val);
    }
}

// ---------------------------------------------------------------- launch
extern "C" void kernel_launch(void* const* d_in, const int* in_sizes, int n_in,
                              void* d_out, int out_size, void* d_ws, size_t ws_size,
                              hipStream_t stream) {
  const float* x    = (const float*)d_in[0];
  // d_in[1] start_pos == 0 (ignored; causal mask implemented directly)
  const float* fcos = (const float*)d_in[2];
  const float* fsin = (const float*)d_in[3];
  // d_in[4] mask == triu(-inf,1) (ignored; equivalent to kv>q test)
  const float* wq   = (const float*)d_in[5];
  const float* wk   = (const float*)d_in[6];
  const float* wv   = (const float*)d_in[7];
  const float* wo   = (const float*)d_in[8];
  float* out = (float*)d_out;

  const size_t XN = (size_t)ROWS * DIM;   // 8388608
  const size_t WN = (size_t)DIM * DIM;    // 4194304
  u16* ws  = (u16*)d_ws;
  u16* xb  = ws;
  u16* wqb = xb + XN;
  u16* wkb = wqb + WN;
  u16* wvb = wkb + WN;
  u16* wob = wvb + WN;
  u16* q   = wob + WN;
  u16* k   = q + XN;
  u16* v   = k + XN;
  u16* ao  = v + XN;

  cvt_kernel<<<(int)(XN / 4 / 256), 256, 0, stream>>>(x, xb, (int)(XN / 4));
  cvt_kernel<<<(int)(WN / 4 / 256), 256, 0, stream>>>(wq, wqb, (int)(WN / 4));
  cvt_kernel<<<(int)(WN / 4 / 256), 256, 0, stream>>>(wk, wkb, (int)(WN / 4));
  cvt_kernel<<<(int)(WN / 4 / 256), 256, 0, stream>>>(wv, wvb, (int)(WN / 4));
  cvt_kernel<<<(int)(WN / 4 / 256), 256, 0, stream>>>(wo, wob, (int)(WN / 4));

  gemm_qkv<<<dim3(DIM / 128, ROWS / 128, 3), 256, 0, stream>>>(xb, wqb, wkb, wvb, q, k, v);

  rope_kernel<<<2 * ROWS * 1024 / 256, 256, 0, stream>>>(q, k, fcos, fsin);

  attn_kernel<<<dim3(SEQ / 64, BSZ * NHEADS), 256, 0, stream>>>(q, k, v, ao);

  gemm_out<<<dim3(DIM / 128, ROWS / 128), 256, 0, stream>>>(ao, wob, out);
}

// Round 2
// 461.763 us; speedup vs baseline: 1.4080x; 1.4080x over previous
//
#include <hip/hip_runtime.h>
#include <stdint.h>

#define DIM 2048
#define SEQ 2048
#define NHEADS 16
#define HDIM 128
#define BSZ 2
#define ROWS (BSZ*SEQ)   // 4096

typedef uint16_t u16;
typedef __attribute__((ext_vector_type(8))) short bf16x8;
typedef __attribute__((ext_vector_type(4))) float fx4;
typedef __attribute__((ext_vector_type(4))) uint16_t u16x4;

typedef const __attribute__((address_space(1))) uint32_t* gp_t;
typedef __attribute__((address_space(3))) uint32_t* lp_t;
// async 16B global->LDS DMA; LDS dest = wave-uniform base + lane*16 (m97/m104)
#define GLL16(g, l) __builtin_amdgcn_global_load_lds((gp_t)(g), (lp_t)(l), 16, 0, 0)

__device__ inline u16 f2bf(float f) {
  union { float f; uint32_t u; } v; v.f = f;
  uint32_t u = v.u;
  u += 0x7FFFu + ((u >> 16) & 1u);   // RNE
  return (u16)(u >> 16);
}
__device__ inline float bf2f(u16 h) {
  union { uint32_t u; float f; } v; v.u = ((uint32_t)h) << 16;
  return v.f;
}

// ---------------------------------------------------------------- convert fp32 -> bf16
__global__ __launch_bounds__(256) void cvt_kernel(const float* __restrict__ src,
                                                  u16* __restrict__ dst, int n4) {
  int i = blockIdx.x * 256 + threadIdx.x;
  if (i >= n4) return;
  fx4 f = *(const fx4*)(src + (size_t)i * 4);
  u16x4 o;
  o[0] = f2bf(f[0]); o[1] = f2bf(f[1]); o[2] = f2bf(f[2]); o[3] = f2bf(f[3]);
  *(u16x4*)(dst + (size_t)i * 4) = o;
}

// ---------------------------------------------------------------- GEMM core (m97 pattern)
// C[M,N] = A[M,K] * B[N,K]^T. 128x128 tile, BK=32, global_load_lds width=16 staging.
// As/Bs [128][32] unpadded: pitch 16 dw -> b128 frag reads land evenly (8 deep/bank = min).
__device__ inline void gemm128_core(const u16* __restrict__ A, const u16* __restrict__ B,
                                    u16 (&As)[128][32], u16 (&Bs)[128][32],
                                    fx4 (&acc)[4][4], int M0, int N0) {
  const int tid  = threadIdx.x;
  const int lane = tid & 63;
  const int wave = tid >> 6;
  const int wm = (wave >> 1) * 64;
  const int wn = (wave & 1) * 64;
  const int l16 = lane & 15;
  const int q8  = (lane >> 4) * 8;
#pragma unroll
  for (int tm = 0; tm < 4; ++tm)
#pragma unroll
    for (int tn = 0; tn < 4; ++tn) acc[tm][tn] = fx4{0.f, 0.f, 0.f, 0.f};

  const int wrow = wave * 32;
  // lane covers row (lane>>2), 8-elem chunk (lane&3) of a 16-row x 32-col slab
  const size_t laneA = (size_t)(M0 + wrow + (lane >> 2)) * DIM + (lane & 3) * 8;
  const size_t laneB = (size_t)(N0 + wrow + (lane >> 2)) * DIM + (lane & 3) * 8;

  for (int k0 = 0; k0 < DIM; k0 += 32) {
    __syncthreads();                       // prior iteration's frag reads done
    GLL16(A + laneA + k0,            &As[wrow][0]);
    GLL16(A + laneA + 16 * DIM + k0, &As[wrow + 16][0]);
    GLL16(B + laneB + k0,            &Bs[wrow][0]);
    GLL16(B + laneB + 16 * DIM + k0, &Bs[wrow + 16][0]);
    __syncthreads();                       // vmcnt drained by barrier -> LDS valid
    bf16x8 af[4], bfr[4];
#pragma unroll
    for (int t = 0; t < 4; ++t) {
      af[t]  = *(const bf16x8*)&As[wm + t * 16 + l16][q8];
      bfr[t] = *(const bf16x8*)&Bs[wn + t * 16 + l16][q8];
    }
#pragma unroll
    for (int tm = 0; tm < 4; ++tm)
#pragma unroll
      for (int tn = 0; tn < 4; ++tn)
        acc[tm][tn] = __builtin_amdgcn_mfma_f32_16x16x32_bf16(af[tm], bfr[tn], acc[tm][tn], 0, 0, 0);
  }
}

__global__ __launch_bounds__(256) void gemm_qkv(const u16* __restrict__ A,
    const u16* __restrict__ B0, const u16* __restrict__ B1, const u16* __restrict__ B2,
    u16* __restrict__ C0, u16* __restrict__ C1, u16* __restrict__ C2) {
  __shared__ __align__(16) u16 As[128][32];
  __shared__ __align__(16) u16 Bs[128][32];
  const u16* B = (blockIdx.z == 0) ? B0 : (blockIdx.z == 1) ? B1 : B2;
  u16* C       = (blockIdx.z == 0) ? C0 : (blockIdx.z == 1) ? C1 : C2;
  const int M0 = blockIdx.y * 128, N0 = blockIdx.x * 128;
  fx4 acc[4][4];
  gemm128_core(A, B, As, Bs, acc, M0, N0);
  const int lane = threadIdx.x & 63, wave = threadIdx.x >> 6;
  const int wm = (wave >> 1) * 64, wn = (wave & 1) * 64;
  const int l16 = lane & 15, quad = lane >> 4;
#pragma unroll
  for (int tm = 0; tm < 4; ++tm)
#pragma unroll
    for (int tn = 0; tn < 4; ++tn)
#pragma unroll
      for (int r = 0; r < 4; ++r) {
        size_t row = (size_t)(M0 + wm + tm * 16 + quad * 4 + r);
        size_t col = (size_t)(N0 + wn + tn * 16 + l16);
        C[row * DIM + col] = f2bf(acc[tm][tn][r]);
      }
}

__global__ __launch_bounds__(256) void gemm_out(const u16* __restrict__ A,
                                                const u16* __restrict__ B,
                                                float* __restrict__ C) {
  __shared__ __align__(16) u16 As[128][32];
  __shared__ __align__(16) u16 Bs[128][32];
  const int M0 = blockIdx.y * 128, N0 = blockIdx.x * 128;
  fx4 acc[4][4];
  gemm128_core(A, B, As, Bs, acc, M0, N0);
  const int lane = threadIdx.x & 63, wave = threadIdx.x >> 6;
  const int wm = (wave >> 1) * 64, wn = (wave & 1) * 64;
  const int l16 = lane & 15, quad = lane >> 4;
#pragma unroll
  for (int tm = 0; tm < 4; ++tm)
#pragma unroll
    for (int tn = 0; tn < 4; ++tn)
#pragma unroll
      for (int r = 0; r < 4; ++r) {
        size_t row = (size_t)(M0 + wm + tm * 16 + quad * 4 + r);
        size_t col = (size_t)(N0 + wn + tn * 16 + l16);
        C[row * DIM + col] = acc[tm][tn][r];
      }
}

// ---------------------------------------------------------------- RoPE (in-place on bf16 Q,K)
__global__ __launch_bounds__(256) void rope_kernel(u16* __restrict__ q, u16* __restrict__ k,
                                                   const float* __restrict__ fcos,
                                                   const float* __restrict__ fsin) {
  int idx = blockIdx.x * 256 + threadIdx.x;
  int t = idx >> 22;
  int p_all = idx & ((1 << 22) - 1);
  u16* ptr = t ? k : q;
  int row = p_all >> 10;
  int r   = p_all & 1023;
  int h   = r >> 6;
  int p   = r & 63;
  int s   = row & (SEQ - 1);
  size_t base = (size_t)row * DIM + h * HDIM + 2 * p;
  float a = bf2f(ptr[base]), b = bf2f(ptr[base + 1]);
  float c = fcos[s * 64 + p], sn = fsin[s * 64 + p];
  ptr[base]     = f2bf(a * c - b * sn);
  ptr[base + 1] = f2bf(a * sn + b * c);
}

// ---------------------------------------------------------------- V transpose: v[b,s,h,d] -> vtg[(bh*128+d)*SEQ + s]
__global__ __launch_bounds__(256) void vtrans_kernel(const u16* __restrict__ v,
                                                     u16* __restrict__ vtg) {
  __shared__ __align__(16) u16 T[128][72];
  const int tid = threadIdx.x;
  const int s0 = blockIdx.x * 64;
  const int bh = blockIdx.y;
  const int b = bh >> 4, h = bh & 15;
  const size_t vb = ((size_t)b * SEQ + s0) * DIM + h * HDIM;
  // coalesced load (rows of 128 d), scatter into transposed LDS
#pragma unroll
  for (int i = 0; i < 4; ++i) {
    int c = i * 256 + tid;
    int s = c >> 4;              // 0..63
    int d0 = (c & 15) * 8;
    bf16x8 x = *(const bf16x8*)(v + vb + (size_t)s * DIM + d0);
#pragma unroll
    for (int j = 0; j < 8; ++j) T[d0 + j][s] = (u16)x[j];
  }
  __syncthreads();
  // coalesced b128 read of transposed rows -> global
  const size_t ob = ((size_t)bh * HDIM) * SEQ + s0;
#pragma unroll
  for (int i = 0; i < 4; ++i) {
    int c = i * 256 + tid;
    int d = c >> 3;              // 0..127
    int s8 = (c & 7) * 8;
    *(bf16x8*)(vtg + ob + (size_t)d * SEQ + s8) = *(const bf16x8*)&T[d][s8];
  }
}

// ---------------------------------------------------------------- flash attention
// 4 waves x 16 q-rows = 64-q block; KV tile 64. Register double-buffer prefetch.
// Heavy tiles first: qt = 31 - blockIdx.y, bh = blockIdx.x.
__global__ __launch_bounds__(256) void attn_kernel(const u16* __restrict__ qm,
                                                   const u16* __restrict__ km,
                                                   const u16* __restrict__ vtg,
                                                   u16* __restrict__ ao) {
  __shared__ __align__(16) u16 Ks[64][136];   // pitch 68 dw -> 2-way even (free)
  __shared__ __align__(16) u16 Vt[128][72];   // pitch 36 dw -> 2-way even
  __shared__ __align__(16) u16 Ps[4][16][72];
  const int tid = threadIdx.x;
  const int lane = tid & 63, wave = tid >> 6;
  const int l16 = lane & 15, quad = lane >> 4;
  const int bh = blockIdx.x;
  const int qt = (SEQ / 64 - 1) - blockIdx.y;   // heavy blocks dispatched first
  const int b = bh >> 4, h = bh & 15;
  const int q0 = qt * 64;
  const size_t brow = (size_t)b * SEQ;
  const int hc = h * HDIM;
  const size_t vbase = (size_t)bh * HDIM * SEQ;

  bf16x8 aq[4];
  {
    size_t qbase = (brow + q0 + wave * 16 + l16) * DIM + hc;
#pragma unroll
    for (int dc = 0; dc < 4; ++dc)
      aq[dc] = *(const bf16x8*)(qm + qbase + dc * 32 + quad * 8);
  }
  fx4 o[8];
#pragma unroll
  for (int i = 0; i < 8; ++i) o[i] = fx4{0.f, 0.f, 0.f, 0.f};
  float mr[4], lr[4];
#pragma unroll
  for (int r = 0; r < 4; ++r) { mr[r] = -3e38f; lr[r] = 0.f; }

  // prefetch tile 0 into registers
  bf16x8 kreg[4], vreg[4];
#pragma unroll
  for (int i = 0; i < 4; ++i) {
    int c = i * 256 + tid;
    kreg[i] = *(const bf16x8*)(km + (brow + (c >> 4)) * DIM + hc + (c & 15) * 8);
    vreg[i] = *(const bf16x8*)(vtg + vbase + (size_t)(c >> 3) * SEQ + (c & 7) * 8);
  }

  for (int kt = 0; kt <= qt; ++kt) {
    __syncthreads();   // prior iteration's LDS frag reads done
    // registers -> LDS (pure b128, no transpose)
#pragma unroll
    for (int i = 0; i < 4; ++i) {
      int c = i * 256 + tid;
      *(bf16x8*)&Ks[c >> 4][(c & 15) * 8] = kreg[i];
      *(bf16x8*)&Vt[c >> 3][(c & 7) * 8] = vreg[i];
    }
    __syncthreads();   // tile visible
    // prefetch next tile (overlaps with the whole compute phase below)
    if (kt < qt) {
      const int kv1 = (kt + 1) * 64;
#pragma unroll
      for (int i = 0; i < 4; ++i) {
        int c = i * 256 + tid;
        kreg[i] = *(const bf16x8*)(km + (brow + kv1 + (c >> 4)) * DIM + hc + (c & 15) * 8);
        vreg[i] = *(const bf16x8*)(vtg + vbase + (size_t)(c >> 3) * SEQ + kv1 + (c & 7) * 8);
      }
    }
    // S = Q K^T (scaled)
    fx4 s[4];
#pragma unroll
    for (int tn = 0; tn < 4; ++tn) {
      fx4 acc = fx4{0.f, 0.f, 0.f, 0.f};
#pragma unroll
      for (int dc = 0; dc < 4; ++dc) {
        bf16x8 bk = *(const bf16x8*)&Ks[tn * 16 + l16][dc * 32 + quad * 8];
        acc = __builtin_amdgcn_mfma_f32_16x16x32_bf16(aq[dc], bk, acc, 0, 0, 0);
      }
      s[tn] = acc * 0.08838834764831845f;   // 1/sqrt(128)
    }
    // causal mask: only the diagonal tile needs it
    if (kt == qt) {
      const int kv0 = kt * 64;
#pragma unroll
      for (int tn = 0; tn < 4; ++tn) {
        int kvpos = kv0 + tn * 16 + l16;
#pragma unroll
        for (int r = 0; r < 4; ++r) {
          int qpos = q0 + wave * 16 + quad * 4 + r;
          if (kvpos > qpos) s[tn][r] = -1e30f;
        }
      }
    }
    // online softmax
    float alpha[4];
#pragma unroll
    for (int r = 0; r < 4; ++r) {
      float t = fmaxf(fmaxf(s[0][r], s[1][r]), fmaxf(s[2][r], s[3][r]));
      t = fmaxf(t, __shfl_xor(t, 1));
      t = fmaxf(t, __shfl_xor(t, 2));
      t = fmaxf(t, __shfl_xor(t, 4));
      t = fmaxf(t, __shfl_xor(t, 8));
      float mnew = fmaxf(mr[r], t);
      alpha[r] = __expf(mr[r] - mnew);
      float sm = 0.f;
#pragma unroll
      for (int tn = 0; tn < 4; ++tn) {
        float p = __expf(s[tn][r] - mnew);
        s[tn][r] = p;
        sm += p;
      }
      sm += __shfl_xor(sm, 1);
      sm += __shfl_xor(sm, 2);
      sm += __shfl_xor(sm, 4);
      sm += __shfl_xor(sm, 8);
      lr[r] = lr[r] * alpha[r] + sm;
      mr[r] = mnew;
    }
    // P: C-layout -> per-wave LDS buffer (A-layout source for PV); no barrier needed
#pragma unroll
    for (int tn = 0; tn < 4; ++tn)
#pragma unroll
      for (int r = 0; r < 4; ++r)
        Ps[wave][quad * 4 + r][tn * 16 + l16] = f2bf(s[tn][r]);
    // rescale O
#pragma unroll
    for (int nt = 0; nt < 8; ++nt) {
      fx4 t = o[nt];
      t[0] *= alpha[0]; t[1] *= alpha[1]; t[2] *= alpha[2]; t[3] *= alpha[3];
      o[nt] = t;
    }
    // O += P V  (Ps is wave-private: lgkmcnt ordering suffices, no barrier)
#pragma unroll
    for (int t2 = 0; t2 < 2; ++t2) {
      bf16x8 ap = *(const bf16x8*)&Ps[wave][l16][t2 * 32 + quad * 8];
#pragma unroll
      for (int nt = 0; nt < 8; ++nt) {
        bf16x8 bv = *(const bf16x8*)&Vt[nt * 16 + l16][t2 * 32 + quad * 8];
        o[nt] = __builtin_amdgcn_mfma_f32_16x16x32_bf16(ap, bv, o[nt], 0, 0, 0);
      }
    }
  }
  // epilogue
#pragma unroll
  for (int nt = 0; nt < 8; ++nt)
#pragma unroll
    for (int r = 0; r < 4; ++r) {
      float val = o[nt][r] / lr[r];
      size_t row = brow + q0 + wave * 16 + quad * 4 + r;
      ao[row * DIM + hc + nt * 16 + l16] = f2bf(val);
    }
}

// ---------------------------------------------------------------- launch
extern "C" void kernel_launch(void* const* d_in, const int* in_sizes, int n_in,
                              void* d_out, int out_size, void* d_ws, size_t ws_size,
                              hipStream_t stream) {
  const float* x    = (const float*)d_in[0];
  const float* fcos = (const float*)d_in[2];
  const float* fsin = (const float*)d_in[3];
  const float* wq   = (const float*)d_in[5];
  const float* wk   = (const float*)d_in[6];
  const float* wv   = (const float*)d_in[7];
  const float* wo   = (const float*)d_in[8];
  float* out = (float*)d_out;

  const size_t XN = (size_t)ROWS * DIM;   // 8388608
  const size_t WN = (size_t)DIM * DIM;    // 4194304
  u16* ws  = (u16*)d_ws;
  u16* xb  = ws;            // also reused as vtg after gemm_qkv (x no longer needed)
  u16* wqb = xb + XN;
  u16* wkb = wqb + WN;
  u16* wvb = wkb + WN;
  u16* wob = wvb + WN;
  u16* q   = wob + WN;
  u16* k   = q + XN;
  u16* v   = k + XN;
  u16* ao  = v + XN;
  u16* vtg = xb;            // alias: 8M u16, written after gemm_qkv consumed xb

  cvt_kernel<<<(int)(XN / 4 / 256), 256, 0, stream>>>(x, xb, (int)(XN / 4));
  cvt_kernel<<<(int)(WN / 4 / 256), 256, 0, stream>>>(wq, wqb, (int)(WN / 4));
  cvt_kernel<<<(int)(WN / 4 / 256), 256, 0, stream>>>(wk, wkb, (int)(WN / 4));
  cvt_kernel<<<(int)(WN / 4 / 256), 256, 0, stream>>>(wv, wvb, (int)(WN / 4));
  cvt_kernel<<<(int)(WN / 4 / 256), 256, 0, stream>>>(wo, wob, (int)(WN / 4));

  gemm_qkv<<<dim3(DIM / 128, ROWS / 128, 3), 256, 0, stream>>>(xb, wqb, wkb, wvb, q, k, v);

  rope_kernel<<<2 * ROWS * 1024 / 256, 256, 0, stream>>>(q, k, fcos, fsin);
  vtrans_kernel<<<dim3(SEQ / 64, BSZ * NHEADS), 256, 0, stream>>>(v, vtg);

  attn_kernel<<<dim3(BSZ * NHEADS, SEQ / 64), 256, 0, stream>>>(q, k, vtg, ao);

  gemm_out<<<dim3(DIM / 128, ROWS / 128), 256, 0, stream>>>(ao, wob, out);
}